// Round 1
// baseline (2981.518 us; speedup 1.0000x reference)
//
#include <hip/hip_runtime.h>

// Mamba3Dcross fused fp32 implementation for gfx950.
//
// Structure:
//   prep kernel:  M_br = fcW_br @ outW_br (3 x 128 x 256)  into d_ws,
//                 and d_out[p][c] = fcb[c]  (output bias init)
//   branch kernel: 3072 blocks (3 branches x 1024 sequences), 256 thr.
//                 Fully fused: in-proj -> conv -> xp-proj -> dt-proj ->
//                 scan -> (out-proj . fc fold) -> atomicAdd into d_out.

#define XC_S 260   // padded row stride for xc/y tile (bank spread + 16B align)
#define DBC_S 40

struct BranchP {
  const float *inW, *convw, *convb, *xpW, *dtW, *dtb, *Alog, *Dp;
};

struct BArgs {
  const float* x;
  BranchP bp[3];
  const float* M;   // 3*128*256 fused (fc . out-proj) weights
  float* out;
};

__device__ __forceinline__ float sigmoidf_(float v) {
  return 1.0f / (1.0f + __expf(-v));
}

extern "C" __global__ void __launch_bounds__(256)
mamba_prep(const float* __restrict__ fcW, const float* __restrict__ fcb,
           const float* __restrict__ oWv, const float* __restrict__ oWh,
           const float* __restrict__ oWd, float* __restrict__ M,
           float* __restrict__ out) {
  int bid = blockIdx.x;
  if (bid < 384) {
    // M[(br*128 + c)][j] = sum_k fcW[c][br*128+k] * outW_br[k][j]
    int br = bid >> 7, c = bid & 127;
    const float* oW = (br == 0) ? oWv : (br == 1) ? oWh : oWd;
    const float* fr = fcW + c * 384 + br * 128;  // uniform per block -> s_loads
    int j = threadIdx.x;
    float acc = 0.f;
    for (int k = 0; k < 128; ++k)
      acc = fmaf(fr[k], oW[k * 256 + j], acc);
    M[bid * 256 + j] = acc;
  } else {
    // out[p][c] = fcb[c]; 4096 blocks x 256 thr x float4 covers 32768*128
    int idx = (bid - 384) * 256 + threadIdx.x;   // float4 index
    int c4 = idx & 31;
    float4 b = *(const float4*)&fcb[c4 * 4];
    ((float4*)out)[idx] = b;
  }
}

extern "C" __global__ void __launch_bounds__(256, 2)
mamba_branch(BArgs a) {
  __shared__ __align__(16) float xs[32 * 128];    // x tile (16 KB)
  __shared__ __align__(16) float xcs[32 * XC_S];  // xc, later y (32.5 KB)
  __shared__ __align__(16) float dbc[32 * DBC_S]; // dt_raw | B | C (5 KB)

  const int tid = threadIdx.x;
  const int bid = blockIdx.x;
  const int br = bid >> 10;
  const int s  = bid & 1023;
  const BranchP P = a.bp[br];

  const int i0 = s >> 5, i1 = s & 31;
  int xbase, xst, obase, ost;
  if (br == 0)      { xbase = i0*4096   + i1*128;  xst = 131072; obase = i0*32   + i1;    ost = 1024; }
  else if (br == 1) { xbase = i0*131072 + i1*128;  xst = 4096;   obase = i0*1024 + i1;    ost = 32; }
  else              { xbase = i0*131072 + i1*4096; xst = 128;    obase = i0*1024 + i1*32; ost = 1; }

  // ---- stage x sequence (32 x 128) into LDS, coalesced float4 ----
  {
    const float* xg = a.x + xbase;
    #pragma unroll
    for (int i = 0; i < 4; ++i) {
      int idx = tid + i * 256;          // float4 index in [0,1024)
      int t = idx >> 5, c4 = idx & 31;
      *(float4*)&xs[t * 128 + c4 * 4] = *(const float4*)&xg[t * xst + c4 * 4];
    }
  }
  __syncthreads();

  // ---- in-proj: thread owns xi column tid and z column tid (rows tid, tid+256 of inW) ----
  float xi[32], zz[32];
  #pragma unroll
  for (int t = 0; t < 32; ++t) { xi[t] = 0.f; zz[t] = 0.f; }
  {
    const float* w1 = P.inW + tid * 128;
    const float* w2 = w1 + 256 * 128;
    for (int kc = 0; kc < 128; kc += 8) {
      float4 a0 = *(const float4*)&w1[kc];
      float4 a1 = *(const float4*)&w1[kc + 4];
      float4 b0 = *(const float4*)&w2[kc];
      float4 b1 = *(const float4*)&w2[kc + 4];
      #pragma unroll
      for (int t = 0; t < 32; ++t) {
        float4 x0 = *(const float4*)&xs[t * 128 + kc];      // broadcast
        float4 x1 = *(const float4*)&xs[t * 128 + kc + 4];  // broadcast
        xi[t] += x0.x*a0.x + x0.y*a0.y + x0.z*a0.z + x0.w*a0.w
               + x1.x*a1.x + x1.y*a1.y + x1.z*a1.z + x1.w*a1.w;
        zz[t] += x0.x*b0.x + x0.y*b0.y + x0.z*b0.z + x0.w*b0.w
               + x1.x*b1.x + x1.y*b1.y + x1.z*b1.z + x1.w*b1.w;
      }
    }
  }

  // ---- depthwise causal conv + silu (fully in-register, channel d = tid) ----
  {
    float4 cw = *(const float4*)&P.convw[tid * 4];
    float cb = P.convb[tid];
    #pragma unroll
    for (int t = 0; t < 32; ++t) {
      float v = cb + cw.w * xi[t];
      if (t >= 1) v += cw.z * xi[t - 1];
      if (t >= 2) v += cw.y * xi[t - 2];
      if (t >= 3) v += cw.x * xi[t - 3];
      v = v * sigmoidf_(v);           // silu
      xcs[t * XC_S + tid] = v;
    }
  }
  __syncthreads();

  // ---- xp-proj: dbc = xc @ xpW.T  (32 x 40) ----
  {
    const int t = tid >> 3;
    const int c0 = tid & 7;
    #pragma unroll
    for (int p = 0; p < 5; ++p) {
      int c = c0 + p * 8;
      const float* wr = P.xpW + c * 256;
      float acc = 0.f;
      for (int k = 0; k < 256; k += 4) {
        float4 w = *(const float4*)&wr[k];
        float4 xv = *(const float4*)&xcs[t * XC_S + k];
        acc += w.x*xv.x + w.y*xv.y + w.z*xv.z + w.w*xv.w;
      }
      dbc[t * DBC_S + c] = acc;
    }
  }
  __syncthreads();

  // ---- dt-proj (+softplus) then SSM scan; thread owns channel d = tid ----
  {
    const int d = tid;
    float4 w0 = *(const float4*)&P.dtW[d * 8];
    float4 w1 = *(const float4*)&P.dtW[d * 8 + 4];
    float bias = P.dtb[d];
    float dtv[32];
    #pragma unroll
    for (int t = 0; t < 32; ++t) {
      float4 q0 = *(const float4*)&dbc[t * DBC_S];
      float4 q1 = *(const float4*)&dbc[t * DBC_S + 4];
      float sv = bias + q0.x*w0.x + q0.y*w0.y + q0.z*w0.z + q0.w*w0.w
                      + q1.x*w1.x + q1.y*w1.y + q1.z*w1.z + q1.w*w1.w;
      dtv[t] = fmaxf(sv, 0.f) + log1pf(__expf(-fabsf(sv)));   // stable softplus
    }
    float A[16];
    #pragma unroll
    for (int n = 0; n < 16; n += 4) {
      float4 al = *(const float4*)&P.Alog[d * 16 + n];
      A[n]   = -__expf(al.x); A[n+1] = -__expf(al.y);
      A[n+2] = -__expf(al.z); A[n+3] = -__expf(al.w);
    }
    float Dpd = P.Dp[d];
    float h[16];
    #pragma unroll
    for (int n = 0; n < 16; ++n) h[n] = 0.f;

    #pragma unroll
    for (int t = 0; t < 32; ++t) {
      float dtt = dtv[t];
      float u = xcs[t * XC_S + d];
      float4 B0 = *(const float4*)&dbc[t * DBC_S + 8];
      float4 B1 = *(const float4*)&dbc[t * DBC_S + 12];
      float4 B2 = *(const float4*)&dbc[t * DBC_S + 16];
      float4 B3 = *(const float4*)&dbc[t * DBC_S + 20];
      float4 C0 = *(const float4*)&dbc[t * DBC_S + 24];
      float4 C1 = *(const float4*)&dbc[t * DBC_S + 28];
      float4 C2 = *(const float4*)&dbc[t * DBC_S + 32];
      float4 C3 = *(const float4*)&dbc[t * DBC_S + 36];
      float coef = dtt * u;
      float y = 0.f;
      h[0]  = __expf(dtt*A[0]) *h[0]  + coef*B0.x;  y += h[0] *C0.x;
      h[1]  = __expf(dtt*A[1]) *h[1]  + coef*B0.y;  y += h[1] *C0.y;
      h[2]  = __expf(dtt*A[2]) *h[2]  + coef*B0.z;  y += h[2] *C0.z;
      h[3]  = __expf(dtt*A[3]) *h[3]  + coef*B0.w;  y += h[3] *C0.w;
      h[4]  = __expf(dtt*A[4]) *h[4]  + coef*B1.x;  y += h[4] *C1.x;
      h[5]  = __expf(dtt*A[5]) *h[5]  + coef*B1.y;  y += h[5] *C1.y;
      h[6]  = __expf(dtt*A[6]) *h[6]  + coef*B1.z;  y += h[6] *C1.z;
      h[7]  = __expf(dtt*A[7]) *h[7]  + coef*B1.w;  y += h[7] *C1.w;
      h[8]  = __expf(dtt*A[8]) *h[8]  + coef*B2.x;  y += h[8] *C2.x;
      h[9]  = __expf(dtt*A[9]) *h[9]  + coef*B2.y;  y += h[9] *C2.y;
      h[10] = __expf(dtt*A[10])*h[10] + coef*B2.z;  y += h[10]*C2.z;
      h[11] = __expf(dtt*A[11])*h[11] + coef*B2.w;  y += h[11]*C2.w;
      h[12] = __expf(dtt*A[12])*h[12] + coef*B3.x;  y += h[12]*C3.x;
      h[13] = __expf(dtt*A[13])*h[13] + coef*B3.y;  y += h[13]*C3.y;
      h[14] = __expf(dtt*A[14])*h[14] + coef*B3.z;  y += h[14]*C3.z;
      h[15] = __expf(dtt*A[15])*h[15] + coef*B3.w;  y += h[15]*C3.w;
      float zv = zz[t];
      float yv = (y + u * Dpd) * (zv * sigmoidf_(zv));  // +skip, silu(z) gate
      xcs[t * XC_S + d] = yv;   // y tile reuses xc slot (same-thread slot)
    }
  }
  __syncthreads();

  // ---- fused (out-proj . fc): y(32x256) @ M_br.T(256x128), atomicAdd into out ----
  {
    const int cg = tid & 31;   // cols cg*4 .. cg*4+3
    const int tg = tid >> 5;   // t = tg*4 .. tg*4+3
    const float* Mb = a.M + br * (128 * 256);
    const float* r0 = Mb + (cg * 4 + 0) * 256;
    const float* r1 = Mb + (cg * 4 + 1) * 256;
    const float* r2 = Mb + (cg * 4 + 2) * 256;
    const float* r3 = Mb + (cg * 4 + 3) * 256;
    float acc[4][4];
    #pragma unroll
    for (int i = 0; i < 4; ++i) {
      #pragma unroll
      for (int j = 0; j < 4; ++j) acc[i][j] = 0.f;
    }
    for (int k = 0; k < 256; k += 4) {
      float4 w0 = *(const float4*)&r0[k];
      float4 w1 = *(const float4*)&r1[k];
      float4 w2 = *(const float4*)&r2[k];
      float4 w3 = *(const float4*)&r3[k];
      #pragma unroll
      for (int tt = 0; tt < 4; ++tt) {
        float4 yv = *(const float4*)&xcs[(tg * 4 + tt) * XC_S + k];
        acc[tt][0] += yv.x*w0.x + yv.y*w0.y + yv.z*w0.z + yv.w*w0.w;
        acc[tt][1] += yv.x*w1.x + yv.y*w1.y + yv.z*w1.z + yv.w*w1.w;
        acc[tt][2] += yv.x*w2.x + yv.y*w2.y + yv.z*w2.z + yv.w*w2.w;
        acc[tt][3] += yv.x*w3.x + yv.y*w3.y + yv.z*w3.z + yv.w*w3.w;
      }
    }
    #pragma unroll
    for (int tt = 0; tt < 4; ++tt) {
      int p = obase + (tg * 4 + tt) * ost;
      float* op = a.out + p * 128 + cg * 4;
      atomicAdd(&op[0], acc[tt][0]);
      atomicAdd(&op[1], acc[tt][1]);
      atomicAdd(&op[2], acc[tt][2]);
      atomicAdd(&op[3], acc[tt][3]);
    }
  }
}

extern "C" void kernel_launch(void* const* d_in, const int* in_sizes, int n_in,
                              void* d_out, int out_size, void* d_ws, size_t ws_size,
                              hipStream_t stream) {
  BArgs a;
  a.x = (const float*)d_in[0];
  for (int b = 0; b < 3; ++b) {
    const int o = 1 + b * 9;
    a.bp[b].inW   = (const float*)d_in[o + 0];
    a.bp[b].convw = (const float*)d_in[o + 1];
    a.bp[b].convb = (const float*)d_in[o + 2];
    a.bp[b].xpW   = (const float*)d_in[o + 3];
    a.bp[b].dtW   = (const float*)d_in[o + 4];
    a.bp[b].dtb   = (const float*)d_in[o + 5];
    a.bp[b].Alog  = (const float*)d_in[o + 6];
    a.bp[b].Dp    = (const float*)d_in[o + 7];
  }
  const float* fcW = (const float*)d_in[28];
  const float* fcb = (const float*)d_in[29];
  float* M = (float*)d_ws;              // 3*128*256 floats = 384 KB
  a.M = M;
  a.out = (float*)d_out;

  mamba_prep<<<4480, 256, 0, stream>>>(
      fcW, fcb, (const float*)d_in[9], (const float*)d_in[18],
      (const float*)d_in[27], M, a.out);
  mamba_branch<<<3072, 256, 0, stream>>>(a);
}

// Round 2
// 2968.593 us; speedup vs baseline: 1.0044x; 1.0044x over previous
//
#include <hip/hip_runtime.h>

// Mamba3Dcross fused fp32 implementation for gfx950.
//
// R2: removed atomicAdd output path (R1 counters: 6.2 GB WRITE_SIZE from
// 12.6M line-granular atomic RMWs -> memory-bound at 35% HBM, 16.8% VALU).
// Branches now store per-branch partials to d_ws with plain float4 stores;
// a final reduce kernel sums partials + fcb into d_out.
//
// Structure:
//   prep kernel:   M_br = fcW_br @ outW_br (3 x 128 x 256) into d_ws
//   branch kernel: 3072 blocks (3 branches x 1024 sequences), 256 thr.
//                  Fully fused: in-proj -> conv -> xp-proj -> dt-proj ->
//                  scan -> (out-proj . fc fold) -> float4 store to partial.
//   reduce kernel: out = fcb + p_v + p_h + p_d  (float4 elementwise)

#define XC_S 260   // padded row stride for xc/y tile (bank spread + 16B align)
#define DBC_S 40
#define NPOS 32768 // 32*32*32 positions

struct BranchP {
  const float *inW, *convw, *convb, *xpW, *dtW, *dtb, *Alog, *Dp;
};

struct BArgs {
  const float* x;
  BranchP bp[3];
  const float* M;   // 3*128*256 fused (fc . out-proj) weights
  float* part;      // 3 * NPOS * 128 partial outputs
};

__device__ __forceinline__ float sigmoidf_(float v) {
  return 1.0f / (1.0f + __expf(-v));
}

extern "C" __global__ void __launch_bounds__(256)
mamba_prep(const float* __restrict__ fcW,
           const float* __restrict__ oWv, const float* __restrict__ oWh,
           const float* __restrict__ oWd, float* __restrict__ M) {
  int bid = blockIdx.x;
  // M[(br*128 + c)][j] = sum_k fcW[c][br*128+k] * outW_br[k][j]
  int br = bid >> 7, c = bid & 127;
  const float* oW = (br == 0) ? oWv : (br == 1) ? oWh : oWd;
  const float* fr = fcW + c * 384 + br * 128;  // uniform per block -> s_loads
  int j = threadIdx.x;
  float acc = 0.f;
  for (int k = 0; k < 128; ++k)
    acc = fmaf(fr[k], oW[k * 256 + j], acc);
  M[bid * 256 + j] = acc;
}

extern "C" __global__ void __launch_bounds__(256)
mamba_reduce(const float* __restrict__ p0, const float* __restrict__ p1,
             const float* __restrict__ p2, const float* __restrict__ fcb,
             float* __restrict__ out) {
  int idx = blockIdx.x * 256 + threadIdx.x;   // float4 index
  int c4 = idx & 31;
  float4 b = *(const float4*)&fcb[c4 * 4];
  float4 v0 = ((const float4*)p0)[idx];
  float4 v1 = ((const float4*)p1)[idx];
  float4 v2 = ((const float4*)p2)[idx];
  float4 r;
  r.x = b.x + v0.x + v1.x + v2.x;
  r.y = b.y + v0.y + v1.y + v2.y;
  r.z = b.z + v0.z + v1.z + v2.z;
  r.w = b.w + v0.w + v1.w + v2.w;
  ((float4*)out)[idx] = r;
}

extern "C" __global__ void __launch_bounds__(256, 2)
mamba_branch(BArgs a) {
  __shared__ __align__(16) float xs[32 * 128];    // x tile (16 KB)
  __shared__ __align__(16) float xcs[32 * XC_S];  // xc, later y (32.5 KB)
  __shared__ __align__(16) float dbc[32 * DBC_S]; // dt_raw | B | C (5 KB)

  const int tid = threadIdx.x;
  const int bid = blockIdx.x;
  const int br = bid >> 10;
  const int s  = bid & 1023;
  const BranchP P = a.bp[br];

  const int i0 = s >> 5, i1 = s & 31;
  int xbase, xst, obase, ost;
  if (br == 0)      { xbase = i0*4096   + i1*128;  xst = 131072; obase = i0*32   + i1;    ost = 1024; }
  else if (br == 1) { xbase = i0*131072 + i1*128;  xst = 4096;   obase = i0*1024 + i1;    ost = 32; }
  else              { xbase = i0*131072 + i1*4096; xst = 128;    obase = i0*1024 + i1*32; ost = 1; }

  // ---- stage x sequence (32 x 128) into LDS, coalesced float4 ----
  {
    const float* xg = a.x + xbase;
    #pragma unroll
    for (int i = 0; i < 4; ++i) {
      int idx = tid + i * 256;          // float4 index in [0,1024)
      int t = idx >> 5, c4 = idx & 31;
      *(float4*)&xs[t * 128 + c4 * 4] = *(const float4*)&xg[t * xst + c4 * 4];
    }
  }
  __syncthreads();

  // ---- in-proj: thread owns xi column tid and z column tid (rows tid, tid+256 of inW) ----
  float xi[32], zz[32];
  #pragma unroll
  for (int t = 0; t < 32; ++t) { xi[t] = 0.f; zz[t] = 0.f; }
  {
    const float* w1 = P.inW + tid * 128;
    const float* w2 = w1 + 256 * 128;
    for (int kc = 0; kc < 128; kc += 8) {
      float4 a0 = *(const float4*)&w1[kc];
      float4 a1 = *(const float4*)&w1[kc + 4];
      float4 b0 = *(const float4*)&w2[kc];
      float4 b1 = *(const float4*)&w2[kc + 4];
      #pragma unroll
      for (int t = 0; t < 32; ++t) {
        float4 x0 = *(const float4*)&xs[t * 128 + kc];      // broadcast
        float4 x1 = *(const float4*)&xs[t * 128 + kc + 4];  // broadcast
        xi[t] += x0.x*a0.x + x0.y*a0.y + x0.z*a0.z + x0.w*a0.w
               + x1.x*a1.x + x1.y*a1.y + x1.z*a1.z + x1.w*a1.w;
        zz[t] += x0.x*b0.x + x0.y*b0.y + x0.z*b0.z + x0.w*b0.w
               + x1.x*b1.x + x1.y*b1.y + x1.z*b1.z + x1.w*b1.w;
      }
    }
  }

  // ---- depthwise causal conv + silu (fully in-register, channel d = tid) ----
  {
    float4 cw = *(const float4*)&P.convw[tid * 4];
    float cb = P.convb[tid];
    #pragma unroll
    for (int t = 0; t < 32; ++t) {
      float v = cb + cw.w * xi[t];
      if (t >= 1) v += cw.z * xi[t - 1];
      if (t >= 2) v += cw.y * xi[t - 2];
      if (t >= 3) v += cw.x * xi[t - 3];
      v = v * sigmoidf_(v);           // silu
      xcs[t * XC_S + tid] = v;
    }
  }
  __syncthreads();

  // ---- xp-proj: dbc = xc @ xpW.T  (32 x 40) ----
  {
    const int t = tid >> 3;
    const int c0 = tid & 7;
    #pragma unroll
    for (int p = 0; p < 5; ++p) {
      int c = c0 + p * 8;
      const float* wr = P.xpW + c * 256;
      float acc = 0.f;
      for (int k = 0; k < 256; k += 4) {
        float4 w = *(const float4*)&wr[k];
        float4 xv = *(const float4*)&xcs[t * XC_S + k];
        acc += w.x*xv.x + w.y*xv.y + w.z*xv.z + w.w*xv.w;
      }
      dbc[t * DBC_S + c] = acc;
    }
  }
  __syncthreads();

  // ---- dt-proj (+softplus) then SSM scan; thread owns channel d = tid ----
  {
    const int d = tid;
    float4 w0 = *(const float4*)&P.dtW[d * 8];
    float4 w1 = *(const float4*)&P.dtW[d * 8 + 4];
    float bias = P.dtb[d];
    float dtv[32];
    #pragma unroll
    for (int t = 0; t < 32; ++t) {
      float4 q0 = *(const float4*)&dbc[t * DBC_S];
      float4 q1 = *(const float4*)&dbc[t * DBC_S + 4];
      float sv = bias + q0.x*w0.x + q0.y*w0.y + q0.z*w0.z + q0.w*w0.w
                      + q1.x*w1.x + q1.y*w1.y + q1.z*w1.z + q1.w*w1.w;
      dtv[t] = fmaxf(sv, 0.f) + log1pf(__expf(-fabsf(sv)));   // stable softplus
    }
    float A[16];
    #pragma unroll
    for (int n = 0; n < 16; n += 4) {
      float4 al = *(const float4*)&P.Alog[d * 16 + n];
      A[n]   = -__expf(al.x); A[n+1] = -__expf(al.y);
      A[n+2] = -__expf(al.z); A[n+3] = -__expf(al.w);
    }
    float Dpd = P.Dp[d];
    float h[16];
    #pragma unroll
    for (int n = 0; n < 16; ++n) h[n] = 0.f;

    #pragma unroll
    for (int t = 0; t < 32; ++t) {
      float dtt = dtv[t];
      float u = xcs[t * XC_S + d];
      float4 B0 = *(const float4*)&dbc[t * DBC_S + 8];
      float4 B1 = *(const float4*)&dbc[t * DBC_S + 12];
      float4 B2 = *(const float4*)&dbc[t * DBC_S + 16];
      float4 B3 = *(const float4*)&dbc[t * DBC_S + 20];
      float4 C0 = *(const float4*)&dbc[t * DBC_S + 24];
      float4 C1 = *(const float4*)&dbc[t * DBC_S + 28];
      float4 C2 = *(const float4*)&dbc[t * DBC_S + 32];
      float4 C3 = *(const float4*)&dbc[t * DBC_S + 36];
      float coef = dtt * u;
      float y = 0.f;
      h[0]  = __expf(dtt*A[0]) *h[0]  + coef*B0.x;  y += h[0] *C0.x;
      h[1]  = __expf(dtt*A[1]) *h[1]  + coef*B0.y;  y += h[1] *C0.y;
      h[2]  = __expf(dtt*A[2]) *h[2]  + coef*B0.z;  y += h[2] *C0.z;
      h[3]  = __expf(dtt*A[3]) *h[3]  + coef*B0.w;  y += h[3] *C0.w;
      h[4]  = __expf(dtt*A[4]) *h[4]  + coef*B1.x;  y += h[4] *C1.x;
      h[5]  = __expf(dtt*A[5]) *h[5]  + coef*B1.y;  y += h[5] *C1.y;
      h[6]  = __expf(dtt*A[6]) *h[6]  + coef*B1.z;  y += h[6] *C1.z;
      h[7]  = __expf(dtt*A[7]) *h[7]  + coef*B1.w;  y += h[7] *C1.w;
      h[8]  = __expf(dtt*A[8]) *h[8]  + coef*B2.x;  y += h[8] *C2.x;
      h[9]  = __expf(dtt*A[9]) *h[9]  + coef*B2.y;  y += h[9] *C2.y;
      h[10] = __expf(dtt*A[10])*h[10] + coef*B2.z;  y += h[10]*C2.z;
      h[11] = __expf(dtt*A[11])*h[11] + coef*B2.w;  y += h[11]*C2.w;
      h[12] = __expf(dtt*A[12])*h[12] + coef*B3.x;  y += h[12]*C3.x;
      h[13] = __expf(dtt*A[13])*h[13] + coef*B3.y;  y += h[13]*C3.y;
      h[14] = __expf(dtt*A[14])*h[14] + coef*B3.z;  y += h[14]*C3.z;
      h[15] = __expf(dtt*A[15])*h[15] + coef*B3.w;  y += h[15]*C3.w;
      float zv = zz[t];
      float yv = (y + u * Dpd) * (zv * sigmoidf_(zv));  // +skip, silu(z) gate
      xcs[t * XC_S + d] = yv;   // y tile reuses xc slot (same-thread slot)
    }
  }
  __syncthreads();

  // ---- fused (out-proj . fc): y(32x256) @ M_br.T(256x128) -> partial store ----
  {
    const int cg = tid & 31;   // cols cg*4 .. cg*4+3
    const int tg = tid >> 5;   // t = tg*4 .. tg*4+3
    const float* Mb = a.M + br * (128 * 256);
    const float* r0 = Mb + (cg * 4 + 0) * 256;
    const float* r1 = Mb + (cg * 4 + 1) * 256;
    const float* r2 = Mb + (cg * 4 + 2) * 256;
    const float* r3 = Mb + (cg * 4 + 3) * 256;
    float acc[4][4];
    #pragma unroll
    for (int i = 0; i < 4; ++i) {
      #pragma unroll
      for (int j = 0; j < 4; ++j) acc[i][j] = 0.f;
    }
    for (int k = 0; k < 256; k += 4) {
      float4 w0 = *(const float4*)&r0[k];
      float4 w1 = *(const float4*)&r1[k];
      float4 w2 = *(const float4*)&r2[k];
      float4 w3 = *(const float4*)&r3[k];
      #pragma unroll
      for (int tt = 0; tt < 4; ++tt) {
        float4 yv = *(const float4*)&xcs[(tg * 4 + tt) * XC_S + k];
        acc[tt][0] += yv.x*w0.x + yv.y*w0.y + yv.z*w0.z + yv.w*w0.w;
        acc[tt][1] += yv.x*w1.x + yv.y*w1.y + yv.z*w1.z + yv.w*w1.w;
        acc[tt][2] += yv.x*w2.x + yv.y*w2.y + yv.z*w2.z + yv.w*w2.w;
        acc[tt][3] += yv.x*w3.x + yv.y*w3.y + yv.z*w3.z + yv.w*w3.w;
      }
    }
    float* pb = a.part + (size_t)br * (NPOS * 128);
    #pragma unroll
    for (int tt = 0; tt < 4; ++tt) {
      int p = obase + (tg * 4 + tt) * ost;
      float4 r;
      r.x = acc[tt][0]; r.y = acc[tt][1]; r.z = acc[tt][2]; r.w = acc[tt][3];
      *(float4*)&pb[p * 128 + cg * 4] = r;
    }
  }
}

extern "C" void kernel_launch(void* const* d_in, const int* in_sizes, int n_in,
                              void* d_out, int out_size, void* d_ws, size_t ws_size,
                              hipStream_t stream) {
  BArgs a;
  a.x = (const float*)d_in[0];
  for (int b = 0; b < 3; ++b) {
    const int o = 1 + b * 9;
    a.bp[b].inW   = (const float*)d_in[o + 0];
    a.bp[b].convw = (const float*)d_in[o + 1];
    a.bp[b].convb = (const float*)d_in[o + 2];
    a.bp[b].xpW   = (const float*)d_in[o + 3];
    a.bp[b].dtW   = (const float*)d_in[o + 4];
    a.bp[b].dtb   = (const float*)d_in[o + 5];
    a.bp[b].Alog  = (const float*)d_in[o + 6];
    a.bp[b].Dp    = (const float*)d_in[o + 7];
  }
  const float* fcW = (const float*)d_in[28];
  const float* fcb = (const float*)d_in[29];
  float* M = (float*)d_ws;                       // 3*128*256 floats = 384 KB
  float* part = (float*)((char*)d_ws + 3 * 128 * 256 * sizeof(float));
  a.M = M;
  a.part = part;

  mamba_prep<<<384, 256, 0, stream>>>(
      fcW, (const float*)d_in[9], (const float*)d_in[18],
      (const float*)d_in[27], M);
  mamba_branch<<<3072, 256, 0, stream>>>(a);
  mamba_reduce<<<NPOS * 128 / 4 / 256, 256, 0, stream>>>(
      part, part + (size_t)NPOS * 128, part + (size_t)2 * NPOS * 128,
      fcb, (float*)d_out);
}

// Round 3
// 1922.732 us; speedup vs baseline: 1.5507x; 1.5439x over previous
//
#include <hip/hip_runtime.h>

// Mamba3Dcross fused fp32 implementation for gfx950.
//
// R3: kill scratch spills. R1/R2 counters showed 6 GB HBM WRITE with only
// 50 MB of program stores (~8 KB/thread) -> private arrays (xi/zz/dtv)
// demoted to scratch, thrashing L2. Restructure:
//   - in-proj chunked (16 t at a time, xi[16]+zz[16] live), x staged in
//     8 KB k-halves, conv fused with 3 carry regs, xc/z written to LDS.
//   - dtv[] eliminated (dt-proj recomputed per-t inside the scan).
//   - z gate read back from LDS; scan keeps only h[16]+A[16] private.
//   - no runtime-indexed kernarg array (field-wise branch select).
// LDS: 8 KB (x-half, aliased by dbc) + 32x260 (xc/y) + 32x256 (z) = 74.2 KB
// -> 2 blocks/CU, 8 waves/CU.

#define XC_S 260   // xc/y row stride: 260%32=4 -> xp-proj rows hit distinct banks
#define DBC_S 40
#define NPOS 32768 // 32*32*32 positions

struct BranchP {
  const float *inW, *convw, *convb, *xpW, *dtW, *dtb, *Alog, *Dp;
};

struct BArgs {
  const float* x;
  BranchP b0, b1, b2;
  const float* M;   // 3*128*256 fused (fc . out-proj) weights
  float* part;      // 3 * NPOS * 128 partial outputs
};

__device__ __forceinline__ float sigmoidf_(float v) {
  return 1.0f / (1.0f + __expf(-v));
}

extern "C" __global__ void __launch_bounds__(256)
mamba_prep(const float* __restrict__ fcW,
           const float* __restrict__ oWv, const float* __restrict__ oWh,
           const float* __restrict__ oWd, float* __restrict__ M) {
  int bid = blockIdx.x;
  // M[(br*128 + c)][j] = sum_k fcW[c][br*128+k] * outW_br[k][j]
  int br = bid >> 7, c = bid & 127;
  const float* oW = (br == 0) ? oWv : (br == 1) ? oWh : oWd;
  const float* fr = fcW + c * 384 + br * 128;
  int j = threadIdx.x;
  float acc = 0.f;
  for (int k = 0; k < 128; ++k)
    acc = fmaf(fr[k], oW[k * 256 + j], acc);
  M[bid * 256 + j] = acc;
}

extern "C" __global__ void __launch_bounds__(256)
mamba_reduce(const float* __restrict__ p0, const float* __restrict__ p1,
             const float* __restrict__ p2, const float* __restrict__ fcb,
             float* __restrict__ out) {
  int idx = blockIdx.x * 256 + threadIdx.x;   // float4 index
  int c4 = idx & 31;
  float4 b = *(const float4*)&fcb[c4 * 4];
  float4 v0 = ((const float4*)p0)[idx];
  float4 v1 = ((const float4*)p1)[idx];
  float4 v2 = ((const float4*)p2)[idx];
  float4 r;
  r.x = b.x + v0.x + v1.x + v2.x;
  r.y = b.y + v0.y + v1.y + v2.y;
  r.z = b.z + v0.z + v1.z + v2.z;
  r.w = b.w + v0.w + v1.w + v2.w;
  ((float4*)out)[idx] = r;
}

extern "C" __global__ void __launch_bounds__(256, 2)
mamba_branch(BArgs a) {
  __shared__ __align__(16) float smA[2048];        // x half-tile; later dbc
  __shared__ __align__(16) float xcs[32 * XC_S];   // xc, later y (33.3 KB)
  __shared__ __align__(16) float zsS[32 * 256];    // raw z (32 KB)
  float* xs = smA;
  float* dbcS = smA;

  const int tid = threadIdx.x;
  const int bid = blockIdx.x;
  const int br = bid >> 10;
  const int s  = bid & 1023;

  // field-wise select (block-uniform) — avoid runtime-indexed kernarg array
  const float* inW   = (br == 0) ? a.b0.inW   : (br == 1) ? a.b1.inW   : a.b2.inW;
  const float* convw = (br == 0) ? a.b0.convw : (br == 1) ? a.b1.convw : a.b2.convw;
  const float* convb = (br == 0) ? a.b0.convb : (br == 1) ? a.b1.convb : a.b2.convb;
  const float* xpW   = (br == 0) ? a.b0.xpW   : (br == 1) ? a.b1.xpW   : a.b2.xpW;
  const float* dtW   = (br == 0) ? a.b0.dtW   : (br == 1) ? a.b1.dtW   : a.b2.dtW;
  const float* dtb   = (br == 0) ? a.b0.dtb   : (br == 1) ? a.b1.dtb   : a.b2.dtb;
  const float* Alog  = (br == 0) ? a.b0.Alog  : (br == 1) ? a.b1.Alog  : a.b2.Alog;
  const float* Dp    = (br == 0) ? a.b0.Dp    : (br == 1) ? a.b1.Dp    : a.b2.Dp;

  const int i0 = s >> 5, i1 = s & 31;
  int xbase, xst, obase, ost;
  if (br == 0)      { xbase = i0*4096   + i1*128;  xst = 131072; obase = i0*32   + i1;    ost = 1024; }
  else if (br == 1) { xbase = i0*131072 + i1*128;  xst = 4096;   obase = i0*1024 + i1;    ost = 32; }
  else              { xbase = i0*131072 + i1*4096; xst = 128;    obase = i0*1024 + i1*32; ost = 1; }

  // ---- in-proj (chunked) + fused conv/silu; xc -> xcs, raw z -> zsS ----
  float4 cwv = *(const float4*)&convw[tid * 4];
  float cb = convb[tid];
  float cm1 = 0.f, cm2 = 0.f, cm3 = 0.f;   // xi carries across t-chunks

  for (int tc = 0; tc < 2; ++tc) {
    float xi[16], zz[16];
    #pragma unroll
    for (int j = 0; j < 16; ++j) { xi[j] = 0.f; zz[j] = 0.f; }

    for (int hf = 0; hf < 2; ++hf) {       // k-half of the 128-wide input
      __syncthreads();                     // previous xs users done
      {
        const float* xg = a.x + xbase + hf * 64;
        #pragma unroll
        for (int i = 0; i < 2; ++i) {
          int idx = tid + i * 256;         // float4 index in [0,512)
          int t = idx >> 4, c4 = idx & 15;
          *(float4*)&xs[t * 64 + c4 * 4] = *(const float4*)&xg[t * xst + c4 * 4];
        }
      }
      __syncthreads();
      const float* w1 = inW + tid * 128 + hf * 64;
      const float* w2 = w1 + 256 * 128;
      for (int kc = 0; kc < 64; kc += 8) {
        float4 a0 = *(const float4*)&w1[kc];
        float4 a1 = *(const float4*)&w1[kc + 4];
        float4 b0 = *(const float4*)&w2[kc];
        float4 b1 = *(const float4*)&w2[kc + 4];
        #pragma unroll
        for (int tt = 0; tt < 16; ++tt) {
          int t = tc * 16 + tt;
          float4 x0 = *(const float4*)&xs[t * 64 + kc];      // broadcast
          float4 x1 = *(const float4*)&xs[t * 64 + kc + 4];  // broadcast
          xi[tt] += x0.x*a0.x + x0.y*a0.y + x0.z*a0.z + x0.w*a0.w
                  + x1.x*a1.x + x1.y*a1.y + x1.z*a1.z + x1.w*a1.w;
          zz[tt] += x0.x*b0.x + x0.y*b0.y + x0.z*b0.z + x0.w*b0.w
                  + x1.x*b1.x + x1.y*b1.y + x1.z*b1.z + x1.w*b1.w;
        }
      }
    }

    // conv + silu for this chunk (carries cover the chunk boundary)
    #pragma unroll
    for (int tt = 0; tt < 16; ++tt) {
      float xm1 = (tt >= 1) ? xi[tt-1] : cm1;
      float xm2 = (tt >= 2) ? xi[tt-2] : ((tt == 1) ? cm1 : cm2);
      float xm3 = (tt >= 3) ? xi[tt-3] : ((tt == 2) ? cm1 : (tt == 1) ? cm2 : cm3);
      float v = cb + cwv.w * xi[tt] + cwv.z * xm1 + cwv.y * xm2 + cwv.x * xm3;
      v = v * sigmoidf_(v);                // silu
      xcs[(tc*16 + tt) * XC_S + tid] = v;
      zsS[(tc*16 + tt) * 256  + tid] = zz[tt];
    }
    cm1 = xi[15]; cm2 = xi[14]; cm3 = xi[13];
  }
  __syncthreads();   // xc visible to all; xs dead -> dbc may reuse smA

  // ---- xp-proj: dbc = xc @ xpW.T  (32 x 40) ----
  {
    const int t = tid >> 3;
    const int c0 = tid & 7;
    #pragma unroll
    for (int p = 0; p < 5; ++p) {
      int c = c0 + p * 8;
      const float* wr = xpW + c * 256;
      float acc = 0.f;
      for (int k = 0; k < 256; k += 4) {
        float4 w = *(const float4*)&wr[k];
        float4 xv = *(const float4*)&xcs[t * XC_S + k];
        acc += w.x*xv.x + w.y*xv.y + w.z*xv.z + w.w*xv.w;
      }
      dbcS[t * DBC_S + c] = acc;
    }
  }
  __syncthreads();

  // ---- scan; thread owns channel d = tid; dt-proj computed per step ----
  {
    const int d = tid;
    float4 w0 = *(const float4*)&dtW[d * 8];
    float4 w1 = *(const float4*)&dtW[d * 8 + 4];
    float bias = dtb[d];
    float A[16];
    #pragma unroll
    for (int n = 0; n < 16; n += 4) {
      float4 al = *(const float4*)&Alog[d * 16 + n];
      A[n]   = -__expf(al.x); A[n+1] = -__expf(al.y);
      A[n+2] = -__expf(al.z); A[n+3] = -__expf(al.w);
    }
    float Dpd = Dp[d];
    float hs[16];
    #pragma unroll
    for (int n = 0; n < 16; ++n) hs[n] = 0.f;

    #pragma unroll 2
    for (int t = 0; t < 32; ++t) {
      float4 q0 = *(const float4*)&dbcS[t * DBC_S];
      float4 q1 = *(const float4*)&dbcS[t * DBC_S + 4];
      float sv = bias + q0.x*w0.x + q0.y*w0.y + q0.z*w0.z + q0.w*w0.w
                      + q1.x*w1.x + q1.y*w1.y + q1.z*w1.z + q1.w*w1.w;
      float dtt = fmaxf(sv, 0.f) + log1pf(__expf(-fabsf(sv)));  // softplus
      float u = xcs[t * XC_S + d];
      float4 B0 = *(const float4*)&dbcS[t * DBC_S + 8];
      float4 B1 = *(const float4*)&dbcS[t * DBC_S + 12];
      float4 B2 = *(const float4*)&dbcS[t * DBC_S + 16];
      float4 B3 = *(const float4*)&dbcS[t * DBC_S + 20];
      float4 C0 = *(const float4*)&dbcS[t * DBC_S + 24];
      float4 C1 = *(const float4*)&dbcS[t * DBC_S + 28];
      float4 C2 = *(const float4*)&dbcS[t * DBC_S + 32];
      float4 C3 = *(const float4*)&dbcS[t * DBC_S + 36];
      float coef = dtt * u;
      float y = 0.f;
      hs[0]  = __expf(dtt*A[0]) *hs[0]  + coef*B0.x;  y += hs[0] *C0.x;
      hs[1]  = __expf(dtt*A[1]) *hs[1]  + coef*B0.y;  y += hs[1] *C0.y;
      hs[2]  = __expf(dtt*A[2]) *hs[2]  + coef*B0.z;  y += hs[2] *C0.z;
      hs[3]  = __expf(dtt*A[3]) *hs[3]  + coef*B0.w;  y += hs[3] *C0.w;
      hs[4]  = __expf(dtt*A[4]) *hs[4]  + coef*B1.x;  y += hs[4] *C1.x;
      hs[5]  = __expf(dtt*A[5]) *hs[5]  + coef*B1.y;  y += hs[5] *C1.y;
      hs[6]  = __expf(dtt*A[6]) *hs[6]  + coef*B1.z;  y += hs[6] *C1.z;
      hs[7]  = __expf(dtt*A[7]) *hs[7]  + coef*B1.w;  y += hs[7] *C1.w;
      hs[8]  = __expf(dtt*A[8]) *hs[8]  + coef*B2.x;  y += hs[8] *C2.x;
      hs[9]  = __expf(dtt*A[9]) *hs[9]  + coef*B2.y;  y += hs[9] *C2.y;
      hs[10] = __expf(dtt*A[10])*hs[10] + coef*B2.z;  y += hs[10]*C2.z;
      hs[11] = __expf(dtt*A[11])*hs[11] + coef*B2.w;  y += hs[11]*C2.w;
      hs[12] = __expf(dtt*A[12])*hs[12] + coef*B3.x;  y += hs[12]*C3.x;
      hs[13] = __expf(dtt*A[13])*hs[13] + coef*B3.y;  y += hs[13]*C3.y;
      hs[14] = __expf(dtt*A[14])*hs[14] + coef*B3.z;  y += hs[14]*C3.z;
      hs[15] = __expf(dtt*A[15])*hs[15] + coef*B3.w;  y += hs[15]*C3.w;
      float zv = zsS[t * 256 + d];
      float yv = (y + u * Dpd) * (zv * sigmoidf_(zv));  // +skip, silu(z) gate
      xcs[t * XC_S + d] = yv;   // y reuses xc slot (same-thread slot)
    }
  }
  __syncthreads();

  // ---- fused (out-proj . fc): y(32x256) @ M_br.T(256x128) -> partial store ----
  {
    const int cg = tid & 31;   // cols cg*4 .. cg*4+3
    const int tg = tid >> 5;   // t = tg*4 .. tg*4+3
    const float* Mb = a.M + br * (128 * 256);
    const float* r0 = Mb + (cg * 4 + 0) * 256;
    const float* r1 = Mb + (cg * 4 + 1) * 256;
    const float* r2 = Mb + (cg * 4 + 2) * 256;
    const float* r3 = Mb + (cg * 4 + 3) * 256;
    float acc[4][4];
    #pragma unroll
    for (int i = 0; i < 4; ++i)
      #pragma unroll
      for (int j = 0; j < 4; ++j) acc[i][j] = 0.f;
    for (int k = 0; k < 256; k += 4) {
      float4 w0 = *(const float4*)&r0[k];
      float4 w1 = *(const float4*)&r1[k];
      float4 w2 = *(const float4*)&r2[k];
      float4 w3 = *(const float4*)&r3[k];
      #pragma unroll
      for (int tt = 0; tt < 4; ++tt) {
        float4 yv = *(const float4*)&xcs[(tg * 4 + tt) * XC_S + k];
        acc[tt][0] += yv.x*w0.x + yv.y*w0.y + yv.z*w0.z + yv.w*w0.w;
        acc[tt][1] += yv.x*w1.x + yv.y*w1.y + yv.z*w1.z + yv.w*w1.w;
        acc[tt][2] += yv.x*w2.x + yv.y*w2.y + yv.z*w2.z + yv.w*w2.w;
        acc[tt][3] += yv.x*w3.x + yv.y*w3.y + yv.z*w3.z + yv.w*w3.w;
      }
    }
    float* pb = a.part + (size_t)br * (NPOS * 128);
    #pragma unroll
    for (int tt = 0; tt < 4; ++tt) {
      int p = obase + (tg * 4 + tt) * ost;
      float4 r;
      r.x = acc[tt][0]; r.y = acc[tt][1]; r.z = acc[tt][2]; r.w = acc[tt][3];
      *(float4*)&pb[p * 128 + cg * 4] = r;
    }
  }
}

extern "C" void kernel_launch(void* const* d_in, const int* in_sizes, int n_in,
                              void* d_out, int out_size, void* d_ws, size_t ws_size,
                              hipStream_t stream) {
  BArgs a;
  a.x = (const float*)d_in[0];
  BranchP* bps[3] = { &a.b0, &a.b1, &a.b2 };
  for (int b = 0; b < 3; ++b) {
    const int o = 1 + b * 9;
    bps[b]->inW   = (const float*)d_in[o + 0];
    bps[b]->convw = (const float*)d_in[o + 1];
    bps[b]->convb = (const float*)d_in[o + 2];
    bps[b]->xpW   = (const float*)d_in[o + 3];
    bps[b]->dtW   = (const float*)d_in[o + 4];
    bps[b]->dtb   = (const float*)d_in[o + 5];
    bps[b]->Alog  = (const float*)d_in[o + 6];
    bps[b]->Dp    = (const float*)d_in[o + 7];
  }
  const float* fcW = (const float*)d_in[28];
  const float* fcb = (const float*)d_in[29];
  float* M = (float*)d_ws;                       // 3*128*256 floats = 384 KB
  float* part = (float*)((char*)d_ws + 3 * 128 * 256 * sizeof(float));
  a.M = M;
  a.part = part;

  mamba_prep<<<384, 256, 0, stream>>>(
      fcW, (const float*)d_in[9], (const float*)d_in[18],
      (const float*)d_in[27], M);
  mamba_branch<<<3072, 256, 0, stream>>>(a);
  mamba_reduce<<<NPOS * 128 / 4 / 256, 256, 0, stream>>>(
      part, part + (size_t)NPOS * 128, part + (size_t)2 * NPOS * 128,
      fcb, (float*)d_out);
}

// Round 4
// 1179.224 us; speedup vs baseline: 2.5284x; 1.6305x over previous
//
#include <hip/hip_runtime.h>

// Mamba3Dcross fused fp32 implementation for gfx950.
//
// R4: kill the REMAINING scratch spill. R3 still wrote 2.17 GB HBM
// (~2.8 KB/thread) with only 50 MB of program stores -> loop-carried hs[]
// spill in the scan (unroll-2 kept ~40 LDS-load dest regs in flight on top
// of hs[16]+A[16]) plus unbounded k-loop unrolling in the GEMM phases.
// Changes:
//   - scan: #pragma unroll 1 + B/C loads split into two n-halves
//   - in-proj / out-proj k-loops: #pragma unroll 2; xp-proj: unroll 4
//   - silu(z) gate computed at in-proj time (scan just multiplies)
// LDS unchanged: 8 KB (x-half / dbc alias) + 32x260 (xc/y) + 32x256 (gate)
// = 74.2 KB -> 2 blocks/CU.

#define XC_S 260   // xc/y row stride: 260%32=4 -> xp-proj rows hit distinct banks
#define DBC_S 40
#define NPOS 32768 // 32*32*32 positions

struct BranchP {
  const float *inW, *convw, *convb, *xpW, *dtW, *dtb, *Alog, *Dp;
};

struct BArgs {
  const float* x;
  BranchP b0, b1, b2;
  const float* M;   // 3*128*256 fused (fc . out-proj) weights
  float* part;      // 3 * NPOS * 128 partial outputs
};

__device__ __forceinline__ float sigmoidf_(float v) {
  return 1.0f / (1.0f + __expf(-v));
}

extern "C" __global__ void __launch_bounds__(256)
mamba_prep(const float* __restrict__ fcW,
           const float* __restrict__ oWv, const float* __restrict__ oWh,
           const float* __restrict__ oWd, float* __restrict__ M) {
  int bid = blockIdx.x;
  // M[(br*128 + c)][j] = sum_k fcW[c][br*128+k] * outW_br[k][j]
  int br = bid >> 7, c = bid & 127;
  const float* oW = (br == 0) ? oWv : (br == 1) ? oWh : oWd;
  const float* fr = fcW + c * 384 + br * 128;
  int j = threadIdx.x;
  float acc = 0.f;
  for (int k = 0; k < 128; ++k)
    acc = fmaf(fr[k], oW[k * 256 + j], acc);
  M[bid * 256 + j] = acc;
}

extern "C" __global__ void __launch_bounds__(256)
mamba_reduce(const float* __restrict__ p0, const float* __restrict__ p1,
             const float* __restrict__ p2, const float* __restrict__ fcb,
             float* __restrict__ out) {
  int idx = blockIdx.x * 256 + threadIdx.x;   // float4 index
  int c4 = idx & 31;
  float4 b = *(const float4*)&fcb[c4 * 4];
  float4 v0 = ((const float4*)p0)[idx];
  float4 v1 = ((const float4*)p1)[idx];
  float4 v2 = ((const float4*)p2)[idx];
  float4 r;
  r.x = b.x + v0.x + v1.x + v2.x;
  r.y = b.y + v0.y + v1.y + v2.y;
  r.z = b.z + v0.z + v1.z + v2.z;
  r.w = b.w + v0.w + v1.w + v2.w;
  ((float4*)out)[idx] = r;
}

extern "C" __global__ void __launch_bounds__(256, 2)
mamba_branch(BArgs a) {
  __shared__ __align__(16) float smA[2048];        // x half-tile; later dbc
  __shared__ __align__(16) float xcs[32 * XC_S];   // xc, later y (33.3 KB)
  __shared__ __align__(16) float zsS[32 * 256];    // silu(z) gate (32 KB)
  float* xs = smA;
  float* dbcS = smA;

  const int tid = threadIdx.x;
  const int bid = blockIdx.x;
  const int br = bid >> 10;
  const int s  = bid & 1023;

  // field-wise select (block-uniform) — avoid runtime-indexed kernarg array
  const float* inW   = (br == 0) ? a.b0.inW   : (br == 1) ? a.b1.inW   : a.b2.inW;
  const float* convw = (br == 0) ? a.b0.convw : (br == 1) ? a.b1.convw : a.b2.convw;
  const float* convb = (br == 0) ? a.b0.convb : (br == 1) ? a.b1.convb : a.b2.convb;
  const float* xpW   = (br == 0) ? a.b0.xpW   : (br == 1) ? a.b1.xpW   : a.b2.xpW;
  const float* dtW   = (br == 0) ? a.b0.dtW   : (br == 1) ? a.b1.dtW   : a.b2.dtW;
  const float* dtb   = (br == 0) ? a.b0.dtb   : (br == 1) ? a.b1.dtb   : a.b2.dtb;
  const float* Alog  = (br == 0) ? a.b0.Alog  : (br == 1) ? a.b1.Alog  : a.b2.Alog;
  const float* Dp    = (br == 0) ? a.b0.Dp    : (br == 1) ? a.b1.Dp    : a.b2.Dp;

  const int i0 = s >> 5, i1 = s & 31;
  int xbase, xst, obase, ost;
  if (br == 0)      { xbase = i0*4096   + i1*128;  xst = 131072; obase = i0*32   + i1;    ost = 1024; }
  else if (br == 1) { xbase = i0*131072 + i1*128;  xst = 4096;   obase = i0*1024 + i1;    ost = 32; }
  else              { xbase = i0*131072 + i1*4096; xst = 128;    obase = i0*1024 + i1*32; ost = 1; }

  // ---- in-proj (chunked) + fused conv/silu; xc -> xcs, silu(z) -> zsS ----
  float4 cwv = *(const float4*)&convw[tid * 4];
  float cb = convb[tid];
  float cm1 = 0.f, cm2 = 0.f, cm3 = 0.f;   // xi carries across t-chunks

  for (int tc = 0; tc < 2; ++tc) {
    float xi[16], zz[16];
    #pragma unroll
    for (int j = 0; j < 16; ++j) { xi[j] = 0.f; zz[j] = 0.f; }

    for (int hf = 0; hf < 2; ++hf) {       // k-half of the 128-wide input
      __syncthreads();                     // previous xs users done
      {
        const float* xg = a.x + xbase + hf * 64;
        #pragma unroll
        for (int i = 0; i < 2; ++i) {
          int idx = tid + i * 256;         // float4 index in [0,512)
          int t = idx >> 4, c4 = idx & 15;
          *(float4*)&xs[t * 64 + c4 * 4] = *(const float4*)&xg[t * xst + c4 * 4];
        }
      }
      __syncthreads();
      const float* w1 = inW + tid * 128 + hf * 64;
      const float* w2 = w1 + 256 * 128;
      #pragma unroll 2
      for (int kc = 0; kc < 64; kc += 8) {
        float4 a0 = *(const float4*)&w1[kc];
        float4 a1 = *(const float4*)&w1[kc + 4];
        float4 b0 = *(const float4*)&w2[kc];
        float4 b1 = *(const float4*)&w2[kc + 4];
        #pragma unroll
        for (int tt = 0; tt < 16; ++tt) {
          int t = tc * 16 + tt;
          float4 x0 = *(const float4*)&xs[t * 64 + kc];      // broadcast
          float4 x1 = *(const float4*)&xs[t * 64 + kc + 4];  // broadcast
          xi[tt] += x0.x*a0.x + x0.y*a0.y + x0.z*a0.z + x0.w*a0.w
                  + x1.x*a1.x + x1.y*a1.y + x1.z*a1.z + x1.w*a1.w;
          zz[tt] += x0.x*b0.x + x0.y*b0.y + x0.z*b0.z + x0.w*b0.w
                  + x1.x*b1.x + x1.y*b1.y + x1.z*b1.z + x1.w*b1.w;
        }
      }
    }

    // conv + silu for this chunk (carries cover the chunk boundary)
    #pragma unroll
    for (int tt = 0; tt < 16; ++tt) {
      float xm1 = (tt >= 1) ? xi[tt-1] : cm1;
      float xm2 = (tt >= 2) ? xi[tt-2] : ((tt == 1) ? cm1 : cm2);
      float xm3 = (tt >= 3) ? xi[tt-3] : ((tt == 2) ? cm1 : (tt == 1) ? cm2 : cm3);
      float v = cb + cwv.w * xi[tt] + cwv.z * xm1 + cwv.y * xm2 + cwv.x * xm3;
      v = v * sigmoidf_(v);                // silu
      xcs[(tc*16 + tt) * XC_S + tid] = v;
      float zv = zz[tt];
      zsS[(tc*16 + tt) * 256  + tid] = zv * sigmoidf_(zv);   // gate precomputed
    }
    cm1 = xi[15]; cm2 = xi[14]; cm3 = xi[13];
  }
  __syncthreads();   // xc visible to all; xs dead -> dbc may reuse smA

  // ---- xp-proj: dbc = xc @ xpW.T  (32 x 40) ----
  {
    const int t = tid >> 3;
    const int c0 = tid & 7;
    #pragma unroll
    for (int p = 0; p < 5; ++p) {
      int c = c0 + p * 8;
      const float* wr = xpW + c * 256;
      float acc = 0.f;
      #pragma unroll 4
      for (int k = 0; k < 256; k += 4) {
        float4 w = *(const float4*)&wr[k];
        float4 xv = *(const float4*)&xcs[t * XC_S + k];
        acc += w.x*xv.x + w.y*xv.y + w.z*xv.z + w.w*xv.w;
      }
      dbcS[t * DBC_S + c] = acc;
    }
  }
  __syncthreads();

  // ---- scan; thread owns channel d = tid; dt-proj computed per step ----
  {
    const int d = tid;
    float4 w0 = *(const float4*)&dtW[d * 8];
    float4 w1 = *(const float4*)&dtW[d * 8 + 4];
    float bias = dtb[d];
    float A[16];
    #pragma unroll
    for (int n = 0; n < 16; n += 4) {
      float4 al = *(const float4*)&Alog[d * 16 + n];
      A[n]   = -__expf(al.x); A[n+1] = -__expf(al.y);
      A[n+2] = -__expf(al.z); A[n+3] = -__expf(al.w);
    }
    float Dpd = Dp[d];
    float hs[16];
    #pragma unroll
    for (int n = 0; n < 16; ++n) hs[n] = 0.f;

    #pragma unroll 1
    for (int t = 0; t < 32; ++t) {
      float4 q0 = *(const float4*)&dbcS[t * DBC_S];
      float4 q1 = *(const float4*)&dbcS[t * DBC_S + 4];
      float sv = bias + q0.x*w0.x + q0.y*w0.y + q0.z*w0.z + q0.w*w0.w
                      + q1.x*w1.x + q1.y*w1.y + q1.z*w1.z + q1.w*w1.w;
      float dtt = fmaxf(sv, 0.f) + log1pf(__expf(-fabsf(sv)));  // softplus
      float u = xcs[t * XC_S + d];
      float coef = dtt * u;
      float y = 0.f;
      {  // n-half 0: peak 16 load regs in flight
        float4 B0 = *(const float4*)&dbcS[t * DBC_S + 8];
        float4 B1 = *(const float4*)&dbcS[t * DBC_S + 12];
        float4 C0 = *(const float4*)&dbcS[t * DBC_S + 24];
        float4 C1 = *(const float4*)&dbcS[t * DBC_S + 28];
        hs[0] = __expf(dtt*A[0])*hs[0] + coef*B0.x;  y += hs[0]*C0.x;
        hs[1] = __expf(dtt*A[1])*hs[1] + coef*B0.y;  y += hs[1]*C0.y;
        hs[2] = __expf(dtt*A[2])*hs[2] + coef*B0.z;  y += hs[2]*C0.z;
        hs[3] = __expf(dtt*A[3])*hs[3] + coef*B0.w;  y += hs[3]*C0.w;
        hs[4] = __expf(dtt*A[4])*hs[4] + coef*B1.x;  y += hs[4]*C1.x;
        hs[5] = __expf(dtt*A[5])*hs[5] + coef*B1.y;  y += hs[5]*C1.y;
        hs[6] = __expf(dtt*A[6])*hs[6] + coef*B1.z;  y += hs[6]*C1.z;
        hs[7] = __expf(dtt*A[7])*hs[7] + coef*B1.w;  y += hs[7]*C1.w;
      }
      {  // n-half 1
        float4 B2 = *(const float4*)&dbcS[t * DBC_S + 16];
        float4 B3 = *(const float4*)&dbcS[t * DBC_S + 20];
        float4 C2 = *(const float4*)&dbcS[t * DBC_S + 32];
        float4 C3 = *(const float4*)&dbcS[t * DBC_S + 36];
        hs[8]  = __expf(dtt*A[8]) *hs[8]  + coef*B2.x;  y += hs[8] *C2.x;
        hs[9]  = __expf(dtt*A[9]) *hs[9]  + coef*B2.y;  y += hs[9] *C2.y;
        hs[10] = __expf(dtt*A[10])*hs[10] + coef*B2.z;  y += hs[10]*C2.z;
        hs[11] = __expf(dtt*A[11])*hs[11] + coef*B2.w;  y += hs[11]*C2.w;
        hs[12] = __expf(dtt*A[12])*hs[12] + coef*B3.x;  y += hs[12]*C3.x;
        hs[13] = __expf(dtt*A[13])*hs[13] + coef*B3.y;  y += hs[13]*C3.y;
        hs[14] = __expf(dtt*A[14])*hs[14] + coef*B3.z;  y += hs[14]*C3.z;
        hs[15] = __expf(dtt*A[15])*hs[15] + coef*B3.w;  y += hs[15]*C3.w;
      }
      float g = zsS[t * 256 + d];
      float yv = (y + u * Dpd) * g;        // +skip, precomputed silu(z) gate
      xcs[t * XC_S + d] = yv;              // y reuses xc slot (same-thread slot)
    }
  }
  __syncthreads();

  // ---- fused (out-proj . fc): y(32x256) @ M_br.T(256x128) -> partial store ----
  {
    const int cg = tid & 31;   // cols cg*4 .. cg*4+3
    const int tg = tid >> 5;   // t = tg*4 .. tg*4+3
    const float* Mb = a.M + br * (128 * 256);
    const float* r0 = Mb + (cg * 4 + 0) * 256;
    const float* r1 = Mb + (cg * 4 + 1) * 256;
    const float* r2 = Mb + (cg * 4 + 2) * 256;
    const float* r3 = Mb + (cg * 4 + 3) * 256;
    float acc[4][4];
    #pragma unroll
    for (int i = 0; i < 4; ++i)
      #pragma unroll
      for (int j = 0; j < 4; ++j) acc[i][j] = 0.f;
    #pragma unroll 2
    for (int k = 0; k < 256; k += 4) {
      float4 w0 = *(const float4*)&r0[k];
      float4 w1 = *(const float4*)&r1[k];
      float4 w2 = *(const float4*)&r2[k];
      float4 w3 = *(const float4*)&r3[k];
      #pragma unroll
      for (int tt = 0; tt < 4; ++tt) {
        float4 yv = *(const float4*)&xcs[(tg * 4 + tt) * XC_S + k];
        acc[tt][0] += yv.x*w0.x + yv.y*w0.y + yv.z*w0.z + yv.w*w0.w;
        acc[tt][1] += yv.x*w1.x + yv.y*w1.y + yv.z*w1.z + yv.w*w1.w;
        acc[tt][2] += yv.x*w2.x + yv.y*w2.y + yv.z*w2.z + yv.w*w2.w;
        acc[tt][3] += yv.x*w3.x + yv.y*w3.y + yv.z*w3.z + yv.w*w3.w;
      }
    }
    float* pb = a.part + (size_t)br * (NPOS * 128);
    #pragma unroll
    for (int tt = 0; tt < 4; ++tt) {
      int p = obase + (tg * 4 + tt) * ost;
      float4 r;
      r.x = acc[tt][0]; r.y = acc[tt][1]; r.z = acc[tt][2]; r.w = acc[tt][3];
      *(float4*)&pb[p * 128 + cg * 4] = r;
    }
  }
}

extern "C" void kernel_launch(void* const* d_in, const int* in_sizes, int n_in,
                              void* d_out, int out_size, void* d_ws, size_t ws_size,
                              hipStream_t stream) {
  BArgs a;
  a.x = (const float*)d_in[0];
  BranchP* bps[3] = { &a.b0, &a.b1, &a.b2 };
  for (int b = 0; b < 3; ++b) {
    const int o = 1 + b * 9;
    bps[b]->inW   = (const float*)d_in[o + 0];
    bps[b]->convw = (const float*)d_in[o + 1];
    bps[b]->convb = (const float*)d_in[o + 2];
    bps[b]->xpW   = (const float*)d_in[o + 3];
    bps[b]->dtW   = (const float*)d_in[o + 4];
    bps[b]->dtb   = (const float*)d_in[o + 5];
    bps[b]->Alog  = (const float*)d_in[o + 6];
    bps[b]->Dp    = (const float*)d_in[o + 7];
  }
  const float* fcW = (const float*)d_in[28];
  const float* fcb = (const float*)d_in[29];
  float* M = (float*)d_ws;                       // 3*128*256 floats = 384 KB
  float* part = (float*)((char*)d_ws + 3 * 128 * 256 * sizeof(float));
  a.M = M;
  a.part = part;

  mamba_prep<<<384, 256, 0, stream>>>(
      fcW, (const float*)d_in[9], (const float*)d_in[18],
      (const float*)d_in[27], M);
  mamba_branch<<<3072, 256, 0, stream>>>(a);
  mamba_reduce<<<NPOS * 128 / 4 / 256, 256, 0, stream>>>(
      part, part + (size_t)NPOS * 128, part + (size_t)2 * NPOS * 128,
      fcb, (float*)d_out);
}